// Round 19
// baseline (80.105 us; speedup 1.0000x reference)
//
#include <hip/hip_runtime.h>

// Capsule routing, MI355X. B=2048, I=64, O=32, DI=DO=16, 3 iters.
// R19 = R17 (passed, 77.8us) + TWO isolated LDS-map changes from R18
// (R18 bundled three changes and failed; the unverified permlane/DPP
// reduction rewrite is excluded here — shfl_xor reductions restored):
//  (2) staging 16 b32 -> 4 b128: x_t col-permuted (col = 4*(e&3)+(e>>2));
//      thread's four m-components contiguous; W e-pairs rearranged to match.
//      Writer quads (il>>1 + ih) sweep all 8 per strided-8 group: conflict-free.
//  (3) p unit = (i>>2)^(d&7)^((i>>5)&1): p-writes sweep all 8 quads
//      (conflict-free), p-reads 2-way (free, m136). Removes R8's 3x2^20.
// Everything else R17 verbatim: NB=64/block, W'=rw+ns precompute, pk_fma
// A-phase, quad-skewed x_t rows, T14 split staging, shfl_xor reductions,
// builtin exp2/rcp/sqrt, straight-line code, no min-wave forcing.

#define THREADS 512

typedef __attribute__((ext_vector_type(2))) float f32x2;
typedef __attribute__((ext_vector_type(4))) float f32x4v;

__global__ __launch_bounds__(256) void wsum_kernel(
    const float* __restrict__ rw, const float* __restrict__ ns,
    float* __restrict__ w2)
{
    const int i = blockIdx.x * 256 + threadIdx.x;   // 131072 float4s
    const float4 a = reinterpret_cast<const float4*>(rw)[i];
    const float4 n = reinterpret_cast<const float4*>(ns)[i];
    float4 r;
    r.x = a.x + n.x;  r.y = a.y + n.y;  r.z = a.z + n.z;  r.w = a.w + n.w;
    reinterpret_cast<float4*>(w2)[i] = r;
}

__device__ __forceinline__ void pk_fma(f32x2& acc, f32x2 a, f32x2 b) {
    asm("v_pk_fma_f32 %0, %1, %2, %0" : "+v"(acc) : "v"(a), "v"(b));
}

template <bool PRE>
__global__ __launch_bounds__(THREADS) void routing_kernel(
    const float* __restrict__ x,    // (B, DI, I) = (2048,16,64)
    const float* __restrict__ rw,   // PRE ? W'=(rw+ns) : rw   (O,I,DO,DI)
    const float* __restrict__ ns,   // unused if PRE
    float* __restrict__ out)        // (1, O, B, DO)
{
    extern __shared__ float lds[];  // [0,8192) p; [8192,16640) x_t
    float* xlds = lds + 8192;       // X(b',i,col): b'*1056 + 16i + 4*(i>>3) + col
                                    // col = 4*(e&3) + (e>>2)

    const int tid  = threadIdx.x;
    const int w    = tid >> 6;      // wave 0..7
    const int lane = tid & 63;      // = i in A-phase

    const int o  = blockIdx.x >> 5;   // o-major: 32 consecutive blocks share W
    const int bc = blockIdx.x & 31;   // 64-b chunk
    const int bbase = bc * 64;

    // ---- W e-pairs matching col-permuted x_t ----
    // read col-quad j gives e {j', 4+j', 8+j', 12+j'}; pairs (e, e+4), (e+8, e+12)
    f32x2 wp0[8], wp1[8];
    {
        const int base = (o * 64 + lane) * 256 + w * 32;
        float4 a0, a1, a2, a3, b0, b1, b2, b3;
        a0 = *reinterpret_cast<const float4*>(rw + base + 0);
        a1 = *reinterpret_cast<const float4*>(rw + base + 4);
        a2 = *reinterpret_cast<const float4*>(rw + base + 8);
        a3 = *reinterpret_cast<const float4*>(rw + base + 12);
        b0 = *reinterpret_cast<const float4*>(rw + base + 16);
        b1 = *reinterpret_cast<const float4*>(rw + base + 20);
        b2 = *reinterpret_cast<const float4*>(rw + base + 24);
        b3 = *reinterpret_cast<const float4*>(rw + base + 28);
        if (!PRE) {
            const float4 n0 = *reinterpret_cast<const float4*>(ns + base + 0);
            const float4 n1 = *reinterpret_cast<const float4*>(ns + base + 4);
            const float4 n2 = *reinterpret_cast<const float4*>(ns + base + 8);
            const float4 n3 = *reinterpret_cast<const float4*>(ns + base + 12);
            const float4 m0 = *reinterpret_cast<const float4*>(ns + base + 16);
            const float4 m1 = *reinterpret_cast<const float4*>(ns + base + 20);
            const float4 m2 = *reinterpret_cast<const float4*>(ns + base + 24);
            const float4 m3 = *reinterpret_cast<const float4*>(ns + base + 28);
            a0.x += n0.x; a0.y += n0.y; a0.z += n0.z; a0.w += n0.w;
            a1.x += n1.x; a1.y += n1.y; a1.z += n1.z; a1.w += n1.w;
            a2.x += n2.x; a2.y += n2.y; a2.z += n2.z; a2.w += n2.w;
            a3.x += n3.x; a3.y += n3.y; a3.z += n3.z; a3.w += n3.w;
            b0.x += m0.x; b0.y += m0.y; b0.z += m0.z; b0.w += m0.w;
            b1.x += m1.x; b1.y += m1.y; b1.z += m1.z; b1.w += m1.w;
            b2.x += m2.x; b2.y += m2.y; b2.z += m2.z; b2.w += m2.w;
            b3.x += m3.x; b3.y += m3.y; b3.z += m3.z; b3.w += m3.w;
        }
        wp0[0] = f32x2{a0.x, a1.x};  wp0[1] = f32x2{a2.x, a3.x};
        wp0[2] = f32x2{a0.y, a1.y};  wp0[3] = f32x2{a2.y, a3.y};
        wp0[4] = f32x2{a0.z, a1.z};  wp0[5] = f32x2{a2.z, a3.z};
        wp0[6] = f32x2{a0.w, a1.w};  wp0[7] = f32x2{a2.w, a3.w};
        wp1[0] = f32x2{b0.x, b1.x};  wp1[1] = f32x2{b2.x, b3.x};
        wp1[2] = f32x2{b0.y, b1.y};  wp1[3] = f32x2{b2.y, b3.y};
        wp1[4] = f32x2{b0.z, b1.z};  wp1[5] = f32x2{b2.z, b3.z};
        wp1[6] = f32x2{b0.w, b1.w};  wp1[7] = f32x2{b2.w, b3.w};
    }

    // ---- p addresses: unit(i,d) = (i>>2) ^ (d&7) ^ ((i>>5)&1) ----
    const int d0 = 2 * w, d1 = 2 * w + 1;
    const int b5 = (lane >> 5) & 1;
    float* pw0 = lds + d0 * 64 + 4 * (((lane >> 2) ^ (d0 & 7)) ^ b5) + (lane & 3);
    float* pw1 = lds + d1 * 64 + 4 * (((lane >> 2) ^ (d1 & 7)) ^ b5) + (lane & 3);

    const int qB  = lane >> 4;      // i-quarter 0..3
    const int dB  = lane & 15;
    const int swz = dB & 7;
    const int qh  = qB >> 1;
    const float4* prbase = reinterpret_cast<const float4*>(lds) + (w * 16 + dB) * 16;
    const float4* pr0 = prbase + (((4 * qB + 0) ^ swz) ^ qh);
    const float4* pr1 = prbase + (((4 * qB + 1) ^ swz) ^ qh);
    const float4* pr2 = prbase + (((4 * qB + 2) ^ swz) ^ qh);
    const float4* pr3 = prbase + (((4 * qB + 3) ^ swz) ^ qh);

    // x_t reads (A-phase): lane = i; base quad-skewed by i>>3
    const float* xrb = xlds + lane * 16 + ((lane >> 3) << 2);

    // x_t staging writes: thread (b=w, il=lane&15, ih=lane>>4) writes rows
    // 4il+m, cols 4ih..4ih+3 as ONE b128 each (col-permuted transpose).
    const int il = lane & 15, ih = lane >> 4;
    float* xws = xlds + w * 1056 + il * 64 + ((il >> 1) << 2) + ih * 4;

    const float4* xsrc0 = reinterpret_cast<const float4*>(x) + bbase * 256
                        + (w * 256 + lane);

    const int outbase = (o * 2048 + bbase + w) * 16 + dB;

    // ---- prologue: stage x-tile 0 (transpose via 4 b128 writes) ----
    float4 xb0 = xsrc0[0];
    float4 xb1 = xsrc0[64];
    float4 xb2 = xsrc0[128];
    float4 xb3 = xsrc0[192];
    *reinterpret_cast<float4*>(xws + 0)  = make_float4(xb0.x, xb1.x, xb2.x, xb3.x);
    *reinterpret_cast<float4*>(xws + 16) = make_float4(xb0.y, xb1.y, xb2.y, xb3.y);
    *reinterpret_cast<float4*>(xws + 32) = make_float4(xb0.z, xb1.z, xb2.z, xb3.z);
    *reinterpret_cast<float4*>(xws + 48) = make_float4(xb0.w, xb1.w, xb2.w, xb3.w);
    __syncthreads();                // x-tile 0 ready

    #pragma unroll
    for (int s = 0; s < 8; ++s) {
        // ---- A-phase: x_t -> p (8 b's; 4 b128 reads, 16 pk_fma each) ----
        #pragma unroll
        for (int bb = 0; bb < 8; ++bb) {
            const f32x4v v0 = *reinterpret_cast<const f32x4v*>(xrb + bb * 1056 + 0);
            const f32x4v v1 = *reinterpret_cast<const f32x4v*>(xrb + bb * 1056 + 4);
            const f32x4v v2 = *reinterpret_cast<const f32x4v*>(xrb + bb * 1056 + 8);
            const f32x4v v3 = *reinterpret_cast<const f32x4v*>(xrb + bb * 1056 + 12);
            const f32x2 x0 = __builtin_shufflevector(v0, v0, 0, 1);  // e 0,4
            const f32x2 x1 = __builtin_shufflevector(v0, v0, 2, 3);  // e 8,12
            const f32x2 x2 = __builtin_shufflevector(v1, v1, 0, 1);  // e 1,5
            const f32x2 x3 = __builtin_shufflevector(v1, v1, 2, 3);  // e 9,13
            const f32x2 x4 = __builtin_shufflevector(v2, v2, 0, 1);  // e 2,6
            const f32x2 x5 = __builtin_shufflevector(v2, v2, 2, 3);  // e 10,14
            const f32x2 x6 = __builtin_shufflevector(v3, v3, 0, 1);  // e 3,7
            const f32x2 x7 = __builtin_shufflevector(v3, v3, 2, 3);  // e 11,15
            f32x2 acc0 = {0.f, 0.f};
            f32x2 acc1 = {0.f, 0.f};
            pk_fma(acc0, wp0[0], x0);  pk_fma(acc1, wp1[0], x0);
            pk_fma(acc0, wp0[1], x1);  pk_fma(acc1, wp1[1], x1);
            pk_fma(acc0, wp0[2], x2);  pk_fma(acc1, wp1[2], x2);
            pk_fma(acc0, wp0[3], x3);  pk_fma(acc1, wp1[3], x3);
            pk_fma(acc0, wp0[4], x4);  pk_fma(acc1, wp1[4], x4);
            pk_fma(acc0, wp0[5], x5);  pk_fma(acc1, wp1[5], x5);
            pk_fma(acc0, wp0[6], x6);  pk_fma(acc1, wp1[6], x6);
            pk_fma(acc0, wp0[7], x7);  pk_fma(acc1, wp1[7], x7);
            pw0[bb * 1024] = acc0[0] + acc0[1];
            pw1[bb * 1024] = acc1[0] + acc1[1];
        }
        __syncthreads();            // p ready; x_t free

        // ---- B-read: p[16] (i = qB*16 + 4jj + m) ----
        float p[16];
        {
            const float4 v0 = *pr0, v1 = *pr1, v2 = *pr2, v3 = *pr3;
            p[0]=v0.x; p[1]=v0.y; p[2]=v0.z; p[3]=v0.w;
            p[4]=v1.x; p[5]=v1.y; p[6]=v1.z; p[7]=v1.w;
            p[8]=v2.x; p[9]=v2.y; p[10]=v2.z; p[11]=v2.w;
            p[12]=v3.x; p[13]=v3.y; p[14]=v3.z; p[15]=v3.w;
        }

        // ---- T14 issue-early: next x-tile global loads ----
        if (s < 7) {
            const float4* xsrc = xsrc0 + (s + 1) * 2048;
            xb0 = xsrc[0];  xb1 = xsrc[64];  xb2 = xsrc[128];  xb3 = xsrc[192];
        }

        // ---- routing iterations (R17 verbatim: shfl_xor reductions) ----
        float t0 = (p[0]+p[1]) + (p[2]+p[3]);
        float t1 = (p[4]+p[5]) + (p[6]+p[7]);
        float t2 = (p[8]+p[9]) + (p[10]+p[11]);
        float t3 = (p[12]+p[13]) + (p[14]+p[15]);
        float part = (t0 + t1) + (t2 + t3);
        part += __shfl_xor(part, 16);
        part += __shfl_xor(part, 32);
        float sv = part * (1.0f / 64.0f);

        float sn = sv * sv;         // squash norm over d (16-lane groups)
        sn += __shfl_xor(sn, 1); sn += __shfl_xor(sn, 2);
        sn += __shfl_xor(sn, 4); sn += __shfl_xor(sn, 8);
        float factor = __builtin_amdgcn_sqrtf(sn)
                     * __builtin_amdgcn_rcpf(1.0f + sn);
        float Vsum = sv * factor;

        #pragma unroll
        for (int it = 0; it < 2; ++it) {
            const float c = Vsum * 1.44269504089f;      // log2(e)
            float e0, e1, e2, e3;
            float dd0, dd1, dd2, dd3, nn0, nn1, nn2, nn3;
            e0 = __builtin_amdgcn_exp2f(p[0] * c);
            e1 = __builtin_amdgcn_exp2f(p[1] * c);
            e2 = __builtin_amdgcn_exp2f(p[2] * c);
            e3 = __builtin_amdgcn_exp2f(p[3] * c);
            dd0 = e0; dd1 = e1; dd2 = e2; dd3 = e3;
            nn0 = e0 * p[0]; nn1 = e1 * p[1]; nn2 = e2 * p[2]; nn3 = e3 * p[3];
            e0 = __builtin_amdgcn_exp2f(p[4] * c);
            e1 = __builtin_amdgcn_exp2f(p[5] * c);
            e2 = __builtin_amdgcn_exp2f(p[6] * c);
            e3 = __builtin_amdgcn_exp2f(p[7] * c);
            dd0 += e0; dd1 += e1; dd2 += e2; dd3 += e3;
            nn0 = fmaf(e0, p[4], nn0); nn1 = fmaf(e1, p[5], nn1);
            nn2 = fmaf(e2, p[6], nn2); nn3 = fmaf(e3, p[7], nn3);
            e0 = __builtin_amdgcn_exp2f(p[8] * c);
            e1 = __builtin_amdgcn_exp2f(p[9] * c);
            e2 = __builtin_amdgcn_exp2f(p[10] * c);
            e3 = __builtin_amdgcn_exp2f(p[11] * c);
            dd0 += e0; dd1 += e1; dd2 += e2; dd3 += e3;
            nn0 = fmaf(e0, p[8], nn0);  nn1 = fmaf(e1, p[9], nn1);
            nn2 = fmaf(e2, p[10], nn2); nn3 = fmaf(e3, p[11], nn3);
            e0 = __builtin_amdgcn_exp2f(p[12] * c);
            e1 = __builtin_amdgcn_exp2f(p[13] * c);
            e2 = __builtin_amdgcn_exp2f(p[14] * c);
            e3 = __builtin_amdgcn_exp2f(p[15] * c);
            dd0 += e0; dd1 += e1; dd2 += e2; dd3 += e3;
            nn0 = fmaf(e0, p[12], nn0); nn1 = fmaf(e1, p[13], nn1);
            nn2 = fmaf(e2, p[14], nn2); nn3 = fmaf(e3, p[15], nn3);

            float den = (dd0 + dd1) + (dd2 + dd3);
            float num = (nn0 + nn1) + (nn2 + nn3);
            den += __shfl_xor(den, 16); den += __shfl_xor(den, 32);
            num += __shfl_xor(num, 16); num += __shfl_xor(num, 32);
            sv = num * __builtin_amdgcn_rcpf(den);
            sn = sv * sv;
            sn += __shfl_xor(sn, 1); sn += __shfl_xor(sn, 2);
            sn += __shfl_xor(sn, 4); sn += __shfl_xor(sn, 8);
            factor = __builtin_amdgcn_sqrtf(sn)
                   * __builtin_amdgcn_rcpf(1.0f + sn);
            Vsum += sv * factor;
        }

        if (qB == 0)
            out[outbase + s * 128] = sv * factor;       // (1,O,B,DO), b=+8 per s

        // ---- T14 write-late: store next x-tile (4 b128 transpose writes) ----
        if (s < 7) {
            *reinterpret_cast<float4*>(xws + 0)  = make_float4(xb0.x, xb1.x, xb2.x, xb3.x);
            *reinterpret_cast<float4*>(xws + 16) = make_float4(xb0.y, xb1.y, xb2.y, xb3.y);
            *reinterpret_cast<float4*>(xws + 32) = make_float4(xb0.z, xb1.z, xb2.z, xb3.z);
            *reinterpret_cast<float4*>(xws + 48) = make_float4(xb0.w, xb1.w, xb2.w, xb3.w);
        }
        __syncthreads();            // p-reads done & next x-tile ready
    }
}

extern "C" void kernel_launch(void* const* d_in, const int* in_sizes, int n_in,
                              void* d_out, int out_size, void* d_ws, size_t ws_size,
                              hipStream_t stream) {
    const float* x  = (const float*)d_in[0];
    const float* rw = (const float*)d_in[1];
    const float* ns = (const float*)d_in[2];
    float* out = (float*)d_out;
    (void)in_sizes; (void)n_in; (void)out_size;

    const int grid = 32 * 32;       // blockIdx = o*32 + bc (64 b per block)
    const size_t w2_bytes = 32u * 64u * 16u * 16u * sizeof(float);  // 2 MB

    if (ws_size >= w2_bytes) {
        float* w2 = (float*)d_ws;
        wsum_kernel<<<512, 256, 0, stream>>>(rw, ns, w2);
        routing_kernel<true><<<grid, THREADS, 66560, stream>>>(x, w2, ns, out);
    } else {
        routing_kernel<false><<<grid, THREADS, 66560, stream>>>(x, rw, ns, out);
    }
}

// Round 20
// 77.780 us; speedup vs baseline: 1.0299x; 1.0299x over previous
//
#include <hip/hip_runtime.h>

// Capsule routing, MI355X. B=2048, I=64, O=32, DI=DO=16, 3 iters.
// R20 = R17 base (77.8us, passed) + xor16/xor32 reduction sums moved from
// DS-pipe shuffles to VALU permlane swaps (gfx950 two-output instrs):
//   auto r = __builtin_amdgcn_permlane16_swap(x, x, false, false);
//   sum16 = r[0] + r[1]   // lane l: x[l] + x[l^16]; permlane32 same for ^32.
// BUILTINS ONLY (R18's raw-asm version failed; R19 isolated the failure to
// that rewrite). __has_builtin-guarded with __shfl_xor fallback -> worst
// case == R17. Removes 10 of 22 DS shuffle ops per thread per sub-round.
// sn's xor1/2/4/8 chain stays __shfl_xor (within-16 swizzles).
// R19's staging-b128 + p-map changes dropped (slightly negative, 80.1us).
// Everything else R17/R14 verbatim (all verified): NB=64/block, W'=rw+ns
// precompute, pk_fma A-phase, quad-skewed x_t, swizzled p, T14 staging,
// builtin exp2/rcp/sqrt, straight-line code, no min-wave forcing.

#define THREADS 512

typedef __attribute__((ext_vector_type(2))) float f32x2;
typedef __attribute__((ext_vector_type(4))) float f32x4v;

__global__ __launch_bounds__(256) void wsum_kernel(
    const float* __restrict__ rw, const float* __restrict__ ns,
    float* __restrict__ w2)
{
    const int i = blockIdx.x * 256 + threadIdx.x;   // 131072 float4s
    const float4 a = reinterpret_cast<const float4*>(rw)[i];
    const float4 n = reinterpret_cast<const float4*>(ns)[i];
    float4 r;
    r.x = a.x + n.x;  r.y = a.y + n.y;  r.z = a.z + n.z;  r.w = a.w + n.w;
    reinterpret_cast<float4*>(w2)[i] = r;
}

__device__ __forceinline__ void pk_fma(f32x2& acc, f32x2 a, f32x2 b) {
    asm("v_pk_fma_f32 %0, %1, %2, %0" : "+v"(acc) : "v"(a), "v"(b));
}

// lane l gets x[l] + x[l^16]  (VALU permlane swap; DS-free)
__device__ __forceinline__ float x16sum(float v) {
#if __has_builtin(__builtin_amdgcn_permlane16_swap)
    auto r = __builtin_amdgcn_permlane16_swap(__float_as_uint(v),
                                              __float_as_uint(v),
                                              false, false);
    return __uint_as_float(r[0]) + __uint_as_float(r[1]);
#else
    return v + __shfl_xor(v, 16);
#endif
}
// lane l gets x[l] + x[l^32]
__device__ __forceinline__ float x32sum(float v) {
#if __has_builtin(__builtin_amdgcn_permlane32_swap)
    auto r = __builtin_amdgcn_permlane32_swap(__float_as_uint(v),
                                              __float_as_uint(v),
                                              false, false);
    return __uint_as_float(r[0]) + __uint_as_float(r[1]);
#else
    return v + __shfl_xor(v, 32);
#endif
}

template <bool PRE>
__global__ __launch_bounds__(THREADS) void routing_kernel(
    const float* __restrict__ x,    // (B, DI, I) = (2048,16,64)
    const float* __restrict__ rw,   // PRE ? W'=(rw+ns) : rw   (O,I,DO,DI)
    const float* __restrict__ ns,   // unused if PRE
    float* __restrict__ out)        // (1, O, B, DO)
{
    extern __shared__ float lds[];  // [0,8192) p; [8192,16640) x_t (skewed)
    float* xlds = lds + 8192;       // X(b',i,e) = b'*1056 + 16i + 4*(i>>3) + e

    const int tid  = threadIdx.x;
    const int w    = tid >> 6;      // wave 0..7
    const int lane = tid & 63;      // = i in A-phase

    const int o  = blockIdx.x >> 5;   // o-major: 32 consecutive blocks share W
    const int bc = blockIdx.x & 31;   // 64-b chunk
    const int bbase = bc * 64;

    // ---- W fragment as e-pairs: lane=i, d in {2w, 2w+1} (32 VGPR) ----
    f32x2 wp0[8], wp1[8];           // wp0[k] = (W[d0][2k], W[d0][2k+1])
    {
        const int base = (o * 64 + lane) * 256 + w * 32;
        #pragma unroll
        for (int eq = 0; eq < 4; ++eq) {
            if (PRE) {
                const float4 a0 = *reinterpret_cast<const float4*>(rw + base + eq * 4);
                wp0[2*eq]   = f32x2{a0.x, a0.y};
                wp0[2*eq+1] = f32x2{a0.z, a0.w};
                const float4 a1 = *reinterpret_cast<const float4*>(rw + base + 16 + eq * 4);
                wp1[2*eq]   = f32x2{a1.x, a1.y};
                wp1[2*eq+1] = f32x2{a1.z, a1.w};
            } else {
                const float4 a0 = *reinterpret_cast<const float4*>(rw + base + eq * 4);
                const float4 n0 = *reinterpret_cast<const float4*>(ns + base + eq * 4);
                wp0[2*eq]   = f32x2{a0.x + n0.x, a0.y + n0.y};
                wp0[2*eq+1] = f32x2{a0.z + n0.z, a0.w + n0.w};
                const float4 a1 = *reinterpret_cast<const float4*>(rw + base + 16 + eq * 4);
                const float4 n1 = *reinterpret_cast<const float4*>(ns + base + 16 + eq * 4);
                wp1[2*eq]   = f32x2{a1.x + n1.x, a1.y + n1.y};
                wp1[2*eq+1] = f32x2{a1.z + n1.z, a1.w + n1.w};
            }
        }
    }

    // ---- precomputed LDS addresses (R12-verified patterns) ----
    const int d0 = 2 * w, d1 = 2 * w + 1;
    float* pw0 = lds + d0 * 64 + ((((lane >> 2) ^ (d0 & 7)) << 2) | (lane & 3));
    float* pw1 = lds + d1 * 64 + ((((lane >> 2) ^ (d1 & 7)) << 2) | (lane & 3));

    const int qB  = lane >> 4;      // i-quarter 0..3
    const int dB  = lane & 15;
    const int swz = dB & 7;
    const float4* prbase = reinterpret_cast<const float4*>(lds) + (w * 16 + dB) * 16;
    const float4* pr0 = prbase + ((4 * qB + 0) ^ swz);
    const float4* pr1 = prbase + ((4 * qB + 1) ^ swz);
    const float4* pr2 = prbase + ((4 * qB + 2) ^ swz);
    const float4* pr3 = prbase + ((4 * qB + 3) ^ swz);

    // x_t reads (A-phase): lane = i; base quad-skewed by i>>3
    const float* xrb = xlds + lane * 16 + ((lane >> 3) << 2);

    // x_t writes (staging): thread holds (b=w, e=4k+ih, i=4il+m)
    const int il = lane & 15, ih = lane >> 4;
    float* xwb = xlds + w * 1056 + il * 64 + ((il >> 1) << 2) + ih;
    float* xw0 = xwb + 0;
    float* xw1 = xwb + 4;
    float* xw2 = xwb + 8;
    float* xw3 = xwb + 12;

    const float4* xsrc0 = reinterpret_cast<const float4*>(x) + bbase * 256
                        + (w * 256 + lane);

    const int outbase = (o * 2048 + bbase + w) * 16 + dB;

    // ---- prologue: stage x-tile 0 (transposed+skewed) ----
    float4 xb0 = xsrc0[0];
    float4 xb1 = xsrc0[64];
    float4 xb2 = xsrc0[128];
    float4 xb3 = xsrc0[192];
    xw0[0] = xb0.x;  xw0[16] = xb0.y;  xw0[32] = xb0.z;  xw0[48] = xb0.w;
    xw1[0] = xb1.x;  xw1[16] = xb1.y;  xw1[32] = xb1.z;  xw1[48] = xb1.w;
    xw2[0] = xb2.x;  xw2[16] = xb2.y;  xw2[32] = xb2.z;  xw2[48] = xb2.w;
    xw3[0] = xb3.x;  xw3[16] = xb3.y;  xw3[32] = xb3.z;  xw3[48] = xb3.w;
    __syncthreads();                // x-tile 0 ready

    #pragma unroll
    for (int s = 0; s < 8; ++s) {
        // ---- A-phase: x_t -> p (8 b's; 4 b128 reads, 16 pk_fma each) ----
        #pragma unroll
        for (int bb = 0; bb < 8; ++bb) {
            const f32x4v v0 = *reinterpret_cast<const f32x4v*>(xrb + bb * 1056 + 0);
            const f32x4v v1 = *reinterpret_cast<const f32x4v*>(xrb + bb * 1056 + 4);
            const f32x4v v2 = *reinterpret_cast<const f32x4v*>(xrb + bb * 1056 + 8);
            const f32x4v v3 = *reinterpret_cast<const f32x4v*>(xrb + bb * 1056 + 12);
            const f32x2 x0 = __builtin_shufflevector(v0, v0, 0, 1);
            const f32x2 x1 = __builtin_shufflevector(v0, v0, 2, 3);
            const f32x2 x2 = __builtin_shufflevector(v1, v1, 0, 1);
            const f32x2 x3 = __builtin_shufflevector(v1, v1, 2, 3);
            const f32x2 x4 = __builtin_shufflevector(v2, v2, 0, 1);
            const f32x2 x5 = __builtin_shufflevector(v2, v2, 2, 3);
            const f32x2 x6 = __builtin_shufflevector(v3, v3, 0, 1);
            const f32x2 x7 = __builtin_shufflevector(v3, v3, 2, 3);
            f32x2 acc0 = {0.f, 0.f};
            f32x2 acc1 = {0.f, 0.f};
            pk_fma(acc0, wp0[0], x0);  pk_fma(acc1, wp1[0], x0);
            pk_fma(acc0, wp0[1], x1);  pk_fma(acc1, wp1[1], x1);
            pk_fma(acc0, wp0[2], x2);  pk_fma(acc1, wp1[2], x2);
            pk_fma(acc0, wp0[3], x3);  pk_fma(acc1, wp1[3], x3);
            pk_fma(acc0, wp0[4], x4);  pk_fma(acc1, wp1[4], x4);
            pk_fma(acc0, wp0[5], x5);  pk_fma(acc1, wp1[5], x5);
            pk_fma(acc0, wp0[6], x6);  pk_fma(acc1, wp1[6], x6);
            pk_fma(acc0, wp0[7], x7);  pk_fma(acc1, wp1[7], x7);
            pw0[bb * 1024] = acc0[0] + acc0[1];
            pw1[bb * 1024] = acc1[0] + acc1[1];
        }
        __syncthreads();            // p ready; x_t free

        // ---- B-read: p[16] (i = qB*16 + 4jj + m) ----
        float p[16];
        {
            const float4 v0 = *pr0, v1 = *pr1, v2 = *pr2, v3 = *pr3;
            p[0]=v0.x; p[1]=v0.y; p[2]=v0.z; p[3]=v0.w;
            p[4]=v1.x; p[5]=v1.y; p[6]=v1.z; p[7]=v1.w;
            p[8]=v2.x; p[9]=v2.y; p[10]=v2.z; p[11]=v2.w;
            p[12]=v3.x; p[13]=v3.y; p[14]=v3.z; p[15]=v3.w;
        }

        // ---- T14 issue-early: next x-tile global loads ----
        if (s < 7) {
            const float4* xsrc = xsrc0 + (s + 1) * 2048;
            xb0 = xsrc[0];  xb1 = xsrc[64];  xb2 = xsrc[128];  xb3 = xsrc[192];
        }

        // ---- routing iterations (xor16/32 sums on VALU permlane) ----
        float t0 = (p[0]+p[1]) + (p[2]+p[3]);
        float t1 = (p[4]+p[5]) + (p[6]+p[7]);
        float t2 = (p[8]+p[9]) + (p[10]+p[11]);
        float t3 = (p[12]+p[13]) + (p[14]+p[15]);
        float part = (t0 + t1) + (t2 + t3);
        part = x32sum(x16sum(part));
        float sv = part * (1.0f / 64.0f);

        float sn = sv * sv;         // squash norm over d (16-lane groups)
        sn += __shfl_xor(sn, 1); sn += __shfl_xor(sn, 2);
        sn += __shfl_xor(sn, 4); sn += __shfl_xor(sn, 8);
        float factor = __builtin_amdgcn_sqrtf(sn)
                     * __builtin_amdgcn_rcpf(1.0f + sn);
        float Vsum = sv * factor;

        #pragma unroll
        for (int it = 0; it < 2; ++it) {
            const float c = Vsum * 1.44269504089f;      // log2(e)
            float e0, e1, e2, e3;
            float dd0, dd1, dd2, dd3, nn0, nn1, nn2, nn3;
            e0 = __builtin_amdgcn_exp2f(p[0] * c);
            e1 = __builtin_amdgcn_exp2f(p[1] * c);
            e2 = __builtin_amdgcn_exp2f(p[2] * c);
            e3 = __builtin_amdgcn_exp2f(p[3] * c);
            dd0 = e0; dd1 = e1; dd2 = e2; dd3 = e3;
            nn0 = e0 * p[0]; nn1 = e1 * p[1]; nn2 = e2 * p[2]; nn3 = e3 * p[3];
            e0 = __builtin_amdgcn_exp2f(p[4] * c);
            e1 = __builtin_amdgcn_exp2f(p[5] * c);
            e2 = __builtin_amdgcn_exp2f(p[6] * c);
            e3 = __builtin_amdgcn_exp2f(p[7] * c);
            dd0 += e0; dd1 += e1; dd2 += e2; dd3 += e3;
            nn0 = fmaf(e0, p[4], nn0); nn1 = fmaf(e1, p[5], nn1);
            nn2 = fmaf(e2, p[6], nn2); nn3 = fmaf(e3, p[7], nn3);
            e0 = __builtin_amdgcn_exp2f(p[8] * c);
            e1 = __builtin_amdgcn_exp2f(p[9] * c);
            e2 = __builtin_amdgcn_exp2f(p[10] * c);
            e3 = __builtin_amdgcn_exp2f(p[11] * c);
            dd0 += e0; dd1 += e1; dd2 += e2; dd3 += e3;
            nn0 = fmaf(e0, p[8], nn0);  nn1 = fmaf(e1, p[9], nn1);
            nn2 = fmaf(e2, p[10], nn2); nn3 = fmaf(e3, p[11], nn3);
            e0 = __builtin_amdgcn_exp2f(p[12] * c);
            e1 = __builtin_amdgcn_exp2f(p[13] * c);
            e2 = __builtin_amdgcn_exp2f(p[14] * c);
            e3 = __builtin_amdgcn_exp2f(p[15] * c);
            dd0 += e0; dd1 += e1; dd2 += e2; dd3 += e3;
            nn0 = fmaf(e0, p[12], nn0); nn1 = fmaf(e1, p[13], nn1);
            nn2 = fmaf(e2, p[14], nn2); nn3 = fmaf(e3, p[15], nn3);

            float den = (dd0 + dd1) + (dd2 + dd3);
            float num = (nn0 + nn1) + (nn2 + nn3);
            den = x32sum(x16sum(den));
            num = x32sum(x16sum(num));
            sv = num * __builtin_amdgcn_rcpf(den);
            sn = sv * sv;
            sn += __shfl_xor(sn, 1); sn += __shfl_xor(sn, 2);
            sn += __shfl_xor(sn, 4); sn += __shfl_xor(sn, 8);
            factor = __builtin_amdgcn_sqrtf(sn)
                   * __builtin_amdgcn_rcpf(1.0f + sn);
            Vsum += sv * factor;
        }

        if (qB == 0)
            out[outbase + s * 128] = sv * factor;       // (1,O,B,DO), b=+8 per s

        // ---- T14 write-late: store next x-tile (transposed+skewed) ----
        if (s < 7) {
            xw0[0] = xb0.x;  xw0[16] = xb0.y;  xw0[32] = xb0.z;  xw0[48] = xb0.w;
            xw1[0] = xb1.x;  xw1[16] = xb1.y;  xw1[32] = xb1.z;  xw1[48] = xb1.w;
            xw2[0] = xb2.x;  xw2[16] = xb2.y;  xw2[32] = xb2.z;  xw2[48] = xb2.w;
            xw3[0] = xb3.x;  xw3[16] = xb3.y;  xw3[32] = xb3.z;  xw3[48] = xb3.w;
        }
        __syncthreads();            // p-reads done & next x-tile ready
    }
}

extern "C" void kernel_launch(void* const* d_in, const int* in_sizes, int n_in,
                              void* d_out, int out_size, void* d_ws, size_t ws_size,
                              hipStream_t stream) {
    const float* x  = (const float*)d_in[0];
    const float* rw = (const float*)d_in[1];
    const float* ns = (const float*)d_in[2];
    float* out = (float*)d_out;
    (void)in_sizes; (void)n_in; (void)out_size;

    const int grid = 32 * 32;       // blockIdx = o*32 + bc (64 b per block)
    const size_t w2_bytes = 32u * 64u * 16u * 16u * sizeof(float);  // 2 MB

    if (ws_size >= w2_bytes) {
        float* w2 = (float*)d_ws;
        wsum_kernel<<<512, 256, 0, stream>>>(rw, ns, w2);
        routing_kernel<true><<<grid, THREADS, 66560, stream>>>(x, w2, ns, out);
    } else {
        routing_kernel<false><<<grid, THREADS, 66560, stream>>>(x, rw, ns, out);
    }
}